// Round 2
// baseline (3232.904 us; speedup 1.0000x reference)
//
#include <hip/hip_runtime.h>

#define NROWS 16384
#define KCODES 8192
#define DDIM 256
#define OUT_LOSS 4194304
#define OUT_CODES 4194305

#define BM 128
#define BN 128
#define BK 16
#define LDT 132   // padded leading dim for LDS tiles [BK][LDT]

// ws layout: [0, 131072) u64 best-keys[16384]; [131072, 196608) f32 x2[16384]

// ---------------- prep: x2 per row (numpy pairwise order), init best keys ----
__global__ __launch_bounds__(256) void vq_prep(const float* __restrict__ z_e,
                                               unsigned long long* __restrict__ best,
                                               float* __restrict__ x2w,
                                               float* __restrict__ out)
{
    const int row = blockIdx.x * 256 + threadIdx.x;
    if (row == 0) out[OUT_LOSS] = 0.0f;
    best[row] = ~0ull;

    const float* rp = z_e + (size_t)row * DDIM;
    float hr[2];
    #pragma unroll
    for (int h = 0; h < 2; ++h) {
        const float* a = rp + h * 128;
        float r[8];
        #pragma unroll
        for (int j = 0; j < 8; ++j) { const float v = a[j]; r[j] = __fmul_rn(v, v); }
        #pragma unroll 1
        for (int i = 8; i < 128; i += 8) {
            #pragma unroll
            for (int j = 0; j < 8; ++j) {
                const float v = a[i + j];
                r[j] = __fadd_rn(r[j], __fmul_rn(v, v));
            }
        }
        hr[h] = __fadd_rn(__fadd_rn(__fadd_rn(r[0], r[1]), __fadd_rn(r[2], r[3])),
                          __fadd_rn(__fadd_rn(r[4], r[5]), __fadd_rn(r[6], r[7])));
    }
    x2w[row] = __fadd_rn(hr[0], hr[1]);
}

// ---------------- main: SGEMM-structured distance + argmin --------------------
// 256 threads, block tile 128 rows x 128 codes, k-loop over D=256 in BK=16
// chunks, 8x8 micro-tile (split 4+4 across the 64-row/64-code halves).
__global__ __launch_bounds__(256, 4) void vq_gemm(const float* __restrict__ z_e,
                                                  const float* __restrict__ emb,
                                                  const float* __restrict__ x2w,
                                                  unsigned long long* __restrict__ best)
{
    __shared__ float As[BK][LDT];
    __shared__ float Bs[BK][LDT];
    __shared__ unsigned long long bestL[BM];

    const int tid  = threadIdx.x;
    const int row0 = blockIdx.x * BM;
    const int kc0  = blockIdx.y * BN;
    const int tx   = tid & 15;
    const int ty   = tid >> 4;

    if (tid < BM) bestL[tid] = ~0ull;

    // staging map: thread -> (row sr / sr+64, d-offset sd), fully coalesced
    const int sr = tid >> 2;          // 0..63
    const int sd = (tid & 3) * 4;     // 0,4,8,12
    const float* aG0 = z_e + (size_t)(row0 + sr) * DDIM + sd;
    const float* aG1 = z_e + (size_t)(row0 + sr + 64) * DDIM + sd;
    const float* bG0 = emb + (size_t)(kc0 + sr) * DDIM + sd;
    const float* bG1 = emb + (size_t)(kc0 + sr + 64) * DDIM + sd;

    float4 pa0 = *(const float4*)(aG0);
    float4 pa1 = *(const float4*)(aG1);
    float4 pb0 = *(const float4*)(bG0);
    float4 pb1 = *(const float4*)(bG1);

    float acc[8][8];
    #pragma unroll
    for (int i = 0; i < 8; ++i)
        #pragma unroll
        for (int j = 0; j < 8; ++j) acc[i][j] = 0.0f;

    #pragma unroll 1
    for (int c = 0; c < DDIM / BK; ++c) {
        __syncthreads();   // previous chunk's reads done before overwrite
        As[sd + 0][sr]      = pa0.x;  As[sd + 1][sr]      = pa0.y;
        As[sd + 2][sr]      = pa0.z;  As[sd + 3][sr]      = pa0.w;
        As[sd + 0][sr + 64] = pa1.x;  As[sd + 1][sr + 64] = pa1.y;
        As[sd + 2][sr + 64] = pa1.z;  As[sd + 3][sr + 64] = pa1.w;
        Bs[sd + 0][sr]      = pb0.x;  Bs[sd + 1][sr]      = pb0.y;
        Bs[sd + 2][sr]      = pb0.z;  Bs[sd + 3][sr]      = pb0.w;
        Bs[sd + 0][sr + 64] = pb1.x;  Bs[sd + 1][sr + 64] = pb1.y;
        Bs[sd + 2][sr + 64] = pb1.z;  Bs[sd + 3][sr + 64] = pb1.w;
        __syncthreads();

        // prefetch next chunk into registers (latency hidden under compute)
        if (c + 1 < DDIM / BK) {
            const int off = (c + 1) * BK;
            pa0 = *(const float4*)(aG0 + off);
            pa1 = *(const float4*)(aG1 + off);
            pb0 = *(const float4*)(bG0 + off);
            pb1 = *(const float4*)(bG1 + off);
        }

        #pragma unroll
        for (int d = 0; d < BK; ++d) {
            const float4 a0 = *(const float4*)&As[d][ty * 4];
            const float4 a1 = *(const float4*)&As[d][ty * 4 + 64];
            const float4 b0 = *(const float4*)&Bs[d][tx * 4];
            const float4 b1 = *(const float4*)&Bs[d][tx * 4 + 64];
            const float av[8] = { a0.x, a0.y, a0.z, a0.w, a1.x, a1.y, a1.z, a1.w };
            const float bv[8] = { b0.x, b0.y, b0.z, b0.w, b1.x, b1.y, b1.z, b1.w };
            #pragma unroll
            for (int i = 0; i < 8; ++i)
                #pragma unroll
                for (int j = 0; j < 8; ++j)
                    acc[i][j] = __fmaf_rn(av[i], bv[j], acc[i][j]);
        }
    }

    // dist = fl(x2 - fl(2*dot)); pack (dist_bits, code) -> u64 min gives the
    // reference's first-index tie-break.
    #pragma unroll
    for (int i = 0; i < 8; ++i) {
        const int r = (i < 4) ? (ty * 4 + i) : (64 + ty * 4 + i - 4);
        const float x2v = x2w[row0 + r];
        unsigned long long key = ~0ull;
        #pragma unroll
        for (int j = 0; j < 8; ++j) {
            const int code = kc0 + ((j < 4) ? (tx * 4 + j) : (64 + tx * 4 + j - 4));
            const float dist = __fsub_rn(x2v, __fmul_rn(2.0f, acc[i][j]));
            const unsigned long long k2 =
                ((unsigned long long)__float_as_uint(dist) << 32) | (unsigned)code;
            key = (k2 < key) ? k2 : key;
        }
        atomicMin(&bestL[r], key);
    }
    __syncthreads();
    if (tid < BM) atomicMin(&best[row0 + tid], bestL[tid]);
}

// ---------------- epilogue: gather z_q, z_q_st, codes, loss ------------------
__global__ __launch_bounds__(256) void vq_epilogue(const float* __restrict__ z_e,
                                                   const float* __restrict__ emb,
                                                   const unsigned long long* __restrict__ best,
                                                   float* __restrict__ out)
{
    const int tid = threadIdx.x;
    float lsum = 0.0f;

    #pragma unroll 1
    for (int r = 0; r < 32; ++r) {
        const int row = blockIdx.x * 32 + r;
        const unsigned code = (unsigned)(best[row] & 0xFFFFFFFFull);
        const float zq = emb[(size_t)code * DDIM + tid];
        const float ze = z_e[(size_t)row * DDIM + tid];
        const float diff = __fsub_rn(zq, ze);
        out[(size_t)row * DDIM + tid] = __fadd_rn(ze, diff);  // z_q_st
        lsum = __fmaf_rn(diff, diff, lsum);
        if (tid == 0) out[OUT_CODES + row] = (float)code;
    }

    #pragma unroll
    for (int o = 32; o > 0; o >>= 1) lsum += __shfl_down(lsum, o);
    __shared__ float wsum[4];
    if ((tid & 63) == 0) wsum[tid >> 6] = lsum;
    __syncthreads();
    if (tid == 0) {
        const float s = (wsum[0] + wsum[1]) + (wsum[2] + wsum[3]);
        // loss = emb_loss + 0.25*commit_loss = 1.25 * mean(diff^2)
        atomicAdd(&out[OUT_LOSS], s * (1.25f / 4194304.0f));
    }
}

extern "C" void kernel_launch(void* const* d_in, const int* in_sizes, int n_in,
                              void* d_out, int out_size, void* d_ws, size_t ws_size,
                              hipStream_t stream) {
    const float* z_e = (const float*)d_in[0];
    const float* emb = (const float*)d_in[1];
    float* out = (float*)d_out;
    unsigned long long* best = (unsigned long long*)d_ws;
    float* x2w = (float*)((char*)d_ws + NROWS * sizeof(unsigned long long));
    (void)in_sizes; (void)n_in; (void)out_size; (void)ws_size;

    vq_prep<<<dim3(NROWS / 256), dim3(256), 0, stream>>>(z_e, best, x2w, out);
    vq_gemm<<<dim3(NROWS / BM, KCODES / BN), dim3(256), 0, stream>>>(z_e, emb, x2w, best);
    vq_epilogue<<<dim3(NROWS / 32), dim3(256), 0, stream>>>(z_e, emb, best, out);
}

// Round 3
// 960.551 us; speedup vs baseline: 3.3657x; 3.3657x over previous
//
#include <hip/hip_runtime.h>

#define NROWS 16384
#define KCODES 8192
#define DDIM 256
#define OUT_LOSS 4194304
#define OUT_CODES 4194305

#define BM 128
#define BN 128
#define BK 16
#define LDT 132   // padded leading dim for LDS tiles [BK][LDT]

// ws layout: [0, 131072) u64 best-keys[16384]; [131072, 196608) f32 x2[16384]

// ---------------- prep: x2 per row (numpy pairwise order), init best keys ----
__global__ __launch_bounds__(256) void vq_prep(const float* __restrict__ z_e,
                                               unsigned long long* __restrict__ best,
                                               float* __restrict__ x2w,
                                               float* __restrict__ out)
{
    const int row = blockIdx.x * 256 + threadIdx.x;
    if (row == 0) out[OUT_LOSS] = 0.0f;
    best[row] = ~0ull;

    const float* rp = z_e + (size_t)row * DDIM;
    float hr[2];
    #pragma unroll
    for (int h = 0; h < 2; ++h) {
        const float* a = rp + h * 128;
        float r[8];
        #pragma unroll
        for (int j = 0; j < 8; ++j) { const float v = a[j]; r[j] = __fmul_rn(v, v); }
        #pragma unroll 1
        for (int i = 8; i < 128; i += 8) {
            #pragma unroll
            for (int j = 0; j < 8; ++j) {
                const float v = a[i + j];
                r[j] = __fadd_rn(r[j], __fmul_rn(v, v));
            }
        }
        hr[h] = __fadd_rn(__fadd_rn(__fadd_rn(r[0], r[1]), __fadd_rn(r[2], r[3])),
                          __fadd_rn(__fadd_rn(r[4], r[5]), __fadd_rn(r[6], r[7])));
    }
    x2w[row] = __fadd_rn(hr[0], hr[1]);
}

// ---------------- main: SGEMM-structured distance + argmin --------------------
// 256 threads, block tile 128 rows x 128 codes, k-loop over D=256 in BK=16
// chunks, 8x8 micro-tile (split 4+4 across the 64-row/64-code halves).
// launch_bounds(256,2): VGPR cap 256 — the 8x8 fp32 tile needs ~120 VGPRs;
// (256,4) made the compiler spill the accumulators (13 GB of scratch HBM
// traffic in R2). Do NOT tighten this without re-checking VGPR_Count.
__global__ __launch_bounds__(256, 2) void vq_gemm(const float* __restrict__ z_e,
                                                  const float* __restrict__ emb,
                                                  const float* __restrict__ x2w,
                                                  unsigned long long* __restrict__ best)
{
    __shared__ float As[BK][LDT];
    __shared__ float Bs[BK][LDT];
    __shared__ unsigned long long bestL[BM];

    const int tid  = threadIdx.x;
    const int row0 = blockIdx.x * BM;
    const int kc0  = blockIdx.y * BN;
    const int tx   = tid & 15;
    const int ty   = tid >> 4;

    if (tid < BM) bestL[tid] = ~0ull;

    // staging map: thread -> (row sr / sr+64, d-offset sd), fully coalesced
    const int sr = tid >> 2;          // 0..63
    const int sd = (tid & 3) * 4;     // 0,4,8,12
    const float* aG0 = z_e + (size_t)(row0 + sr) * DDIM + sd;
    const float* aG1 = z_e + (size_t)(row0 + sr + 64) * DDIM + sd;
    const float* bG0 = emb + (size_t)(kc0 + sr) * DDIM + sd;
    const float* bG1 = emb + (size_t)(kc0 + sr + 64) * DDIM + sd;

    float4 pa0 = *(const float4*)(aG0);
    float4 pa1 = *(const float4*)(aG1);
    float4 pb0 = *(const float4*)(bG0);
    float4 pb1 = *(const float4*)(bG1);

    float acc[8][8];
    #pragma unroll
    for (int i = 0; i < 8; ++i)
        #pragma unroll
        for (int j = 0; j < 8; ++j) acc[i][j] = 0.0f;

    #pragma unroll 1
    for (int c = 0; c < DDIM / BK; ++c) {
        __syncthreads();   // previous chunk's reads done before overwrite
        As[sd + 0][sr]      = pa0.x;  As[sd + 1][sr]      = pa0.y;
        As[sd + 2][sr]      = pa0.z;  As[sd + 3][sr]      = pa0.w;
        As[sd + 0][sr + 64] = pa1.x;  As[sd + 1][sr + 64] = pa1.y;
        As[sd + 2][sr + 64] = pa1.z;  As[sd + 3][sr + 64] = pa1.w;
        Bs[sd + 0][sr]      = pb0.x;  Bs[sd + 1][sr]      = pb0.y;
        Bs[sd + 2][sr]      = pb0.z;  Bs[sd + 3][sr]      = pb0.w;
        Bs[sd + 0][sr + 64] = pb1.x;  Bs[sd + 1][sr + 64] = pb1.y;
        Bs[sd + 2][sr + 64] = pb1.z;  Bs[sd + 3][sr + 64] = pb1.w;
        __syncthreads();

        // prefetch next chunk into registers (latency hidden under compute)
        if (c + 1 < DDIM / BK) {
            const int off = (c + 1) * BK;
            pa0 = *(const float4*)(aG0 + off);
            pa1 = *(const float4*)(aG1 + off);
            pb0 = *(const float4*)(bG0 + off);
            pb1 = *(const float4*)(bG1 + off);
        }

        #pragma unroll
        for (int d = 0; d < BK; ++d) {
            const float4 a0 = *(const float4*)&As[d][ty * 4];
            const float4 a1 = *(const float4*)&As[d][ty * 4 + 64];
            const float4 b0 = *(const float4*)&Bs[d][tx * 4];
            const float4 b1 = *(const float4*)&Bs[d][tx * 4 + 64];
            const float av[8] = { a0.x, a0.y, a0.z, a0.w, a1.x, a1.y, a1.z, a1.w };
            const float bv[8] = { b0.x, b0.y, b0.z, b0.w, b1.x, b1.y, b1.z, b1.w };
            #pragma unroll
            for (int i = 0; i < 8; ++i)
                #pragma unroll
                for (int j = 0; j < 8; ++j)
                    acc[i][j] = __fmaf_rn(av[i], bv[j], acc[i][j]);
        }
    }

    // dist = fl(x2 - fl(2*dot)); pack (dist_bits, code) -> u64 min gives the
    // reference's first-index tie-break.
    #pragma unroll
    for (int i = 0; i < 8; ++i) {
        const int r = (i < 4) ? (ty * 4 + i) : (64 + ty * 4 + i - 4);
        const float x2v = x2w[row0 + r];
        unsigned long long key = ~0ull;
        #pragma unroll
        for (int j = 0; j < 8; ++j) {
            const int code = kc0 + ((j < 4) ? (tx * 4 + j) : (64 + tx * 4 + j - 4));
            const float dist = __fsub_rn(x2v, __fmul_rn(2.0f, acc[i][j]));
            const unsigned long long k2 =
                ((unsigned long long)__float_as_uint(dist) << 32) | (unsigned)code;
            key = (k2 < key) ? k2 : key;
        }
        atomicMin(&bestL[r], key);
    }
    __syncthreads();
    if (tid < BM) atomicMin(&best[row0 + tid], bestL[tid]);
}

// ---------------- epilogue: gather z_q, z_q_st, codes, loss ------------------
__global__ __launch_bounds__(256) void vq_epilogue(const float* __restrict__ z_e,
                                                   const float* __restrict__ emb,
                                                   const unsigned long long* __restrict__ best,
                                                   float* __restrict__ out)
{
    const int tid = threadIdx.x;
    float lsum = 0.0f;

    #pragma unroll 1
    for (int r = 0; r < 32; ++r) {
        const int row = blockIdx.x * 32 + r;
        const unsigned code = (unsigned)(best[row] & 0xFFFFFFFFull);
        const float zq = emb[(size_t)code * DDIM + tid];
        const float ze = z_e[(size_t)row * DDIM + tid];
        const float diff = __fsub_rn(zq, ze);
        out[(size_t)row * DDIM + tid] = __fadd_rn(ze, diff);  // z_q_st
        lsum = __fmaf_rn(diff, diff, lsum);
        if (tid == 0) out[OUT_CODES + row] = (float)code;
    }

    #pragma unroll
    for (int o = 32; o > 0; o >>= 1) lsum += __shfl_down(lsum, o);
    __shared__ float wsum[4];
    if ((tid & 63) == 0) wsum[tid >> 6] = lsum;
    __syncthreads();
    if (tid == 0) {
        const float s = (wsum[0] + wsum[1]) + (wsum[2] + wsum[3]);
        // loss = emb_loss + 0.25*commit_loss = 1.25 * mean(diff^2)
        atomicAdd(&out[OUT_LOSS], s * (1.25f / 4194304.0f));
    }
}

extern "C" void kernel_launch(void* const* d_in, const int* in_sizes, int n_in,
                              void* d_out, int out_size, void* d_ws, size_t ws_size,
                              hipStream_t stream) {
    const float* z_e = (const float*)d_in[0];
    const float* emb = (const float*)d_in[1];
    float* out = (float*)d_out;
    unsigned long long* best = (unsigned long long*)d_ws;
    float* x2w = (float*)((char*)d_ws + NROWS * sizeof(unsigned long long));
    (void)in_sizes; (void)n_in; (void)out_size; (void)ws_size;

    vq_prep<<<dim3(NROWS / 256), dim3(256), 0, stream>>>(z_e, best, x2w, out);
    vq_gemm<<<dim3(NROWS / BM, KCODES / BN), dim3(256), 0, stream>>>(z_e, emb, x2w, best);
    vq_epilogue<<<dim3(NROWS / 32), dim3(256), 0, stream>>>(z_e, emb, best, out);
}